// Round 11
// baseline (557.716 us; speedup 1.0000x reference)
//
#include <hip/hip_runtime.h>
#include <hip/hip_fp16.h>
#include <math.h>

// GCN 2-layer (DGL GraphConv norm='both'). Round-11 restructure:
//  - CSR sort REPLACED by single bin-partition (256-node dst bins) with
//    DETERMINISTIC per-(bin,block) scatter bases (hist matrix + scan) -> the
//    partition pass has ZERO global atomics and no contended reservations.
//  - finalize/csr_src/row_start/in_deg deleted: agg kernels consume the
//    bin-partitioned `packed` array directly, accumulating into LDS
//    (acc[256][65] f32, pad-65 => ~2-way LDS bank aliasing = free).
//  - no memsets at all: every workspace word is written before it is read.
// Pipeline: hist(782) -> scan(2) -> partition(782) -> srcfin(196) ->
//           featw1(12500) -> agg1(196, 68KB LDS) -> agg2(196)
// Requires N <= 131072 (src in 17 bits of packed word). N=50000, E=800000.

#define BS 256
#define EPB 1024          // edges per hist/partition block
#define EPT (EPB / BS)    // 4 edges per thread
#define STR 65            // padded LDS accumulator row stride (floats)

// ---- per-block LDS hist of dst>>8 / src>>8 -> count matrix [bin][block] ----
__global__ void hist_kernel(const int* __restrict__ src, const int* __restrict__ dst,
                            int* __restrict__ countsD, int* __restrict__ countsS,
                            int E, int NB, int TD) {
    __shared__ int hD[256];
    __shared__ int hS[256];
    int tid = threadIdx.x;
    hD[tid] = 0; hS[tid] = 0;
    __syncthreads();
    int base = blockIdx.x * EPB;
    #pragma unroll
    for (int it = 0; it < EPT; it++) {
        int e = base + it * BS + tid;
        if (e < E) {
            atomicAdd(&hD[dst[e] >> 8], 1);
            atomicAdd(&hS[src[e] >> 8], 1);
        }
    }
    __syncthreads();
    if (tid < NB) {
        countsD[(size_t)tid * TD + blockIdx.x] = hD[tid];
        countsS[(size_t)tid * TD + blockIdx.x] = hS[tid];
    }
}

// ---- scan: counts matrix -> in-place per-(bin,block) bases + binBase ----
// block 0 = dst side, block 1 = src side. Thread t owns bin t's row.
__global__ void scan_kernel(int* __restrict__ countsD, int* __restrict__ countsS,
                            int* __restrict__ dstBinBase, int* __restrict__ srcBinBase,
                            int NB, int TD) {
    int* cnts    = (blockIdx.x == 0) ? countsD : countsS;
    int* binBase = (blockIdx.x == 0) ? dstBinBase : srcBinBase;
    __shared__ int s[256];
    int t = threadIdx.x;
    int sum = 0;
    if (t < NB) {
        int* row = cnts + (size_t)t * TD;
        #pragma unroll 8
        for (int i = 0; i < TD; i++) sum += row[i];
    }
    s[t] = sum; __syncthreads();
    for (int off = 1; off < 256; off <<= 1) {
        int u = (t >= off) ? s[t - off] : 0; __syncthreads();
        s[t] += u; __syncthreads();
    }
    int ex = s[t] - sum;                 // exclusive prefix over bins
    if (t < NB) {
        binBase[t] = ex;
        if (t == NB - 1) binBase[NB] = s[t];
        int* row = cnts + (size_t)t * TD;
        int run = ex;
        #pragma unroll 8
        for (int i = 0; i < TD; i++) { int c = row[i]; row[i] = run; run += c; }
    }
}

// ---- partition: scatter edges into dst bins + src-low bytes into src bins ----
// Deterministic bases: NO global atomics anywhere in this kernel.
__global__ void partition_kernel(const int* __restrict__ src, const int* __restrict__ dst,
                                 const int* __restrict__ basesD, const int* __restrict__ basesS,
                                 int* __restrict__ packed, unsigned char* __restrict__ srcPart,
                                 int E, int NB, int TD) {
    __shared__ int curD[256];
    __shared__ int curS[256];
    int tid = threadIdx.x;
    int b = blockIdx.x;
    if (tid < NB) {
        curD[tid] = basesD[(size_t)tid * TD + b];
        curS[tid] = basesS[(size_t)tid * TD + b];
    }
    __syncthreads();
    int base = b * EPB;
    #pragma unroll
    for (int it = 0; it < EPT; it++) {
        int e = base + it * BS + tid;
        if (e < E) {
            int d = dst[e], s2 = src[e];
            int pos = atomicAdd(&curD[d >> 8], 1);       // LDS atomic only
            packed[pos] = s2 | ((d & 255) << 17);
            int pos2 = atomicAdd(&curS[s2 >> 8], 1);
            srcPart[pos2] = (unsigned char)(s2 & 255);
        }
    }
}

// ---- srcfin: per src-bin LDS hist -> out_norm ----
__global__ void srcfin_kernel(const int* __restrict__ srcBinBase,
                              const unsigned char* __restrict__ srcPart,
                              float* __restrict__ out_norm, int N, int NB) {
    __shared__ int h[256];
    int tid = threadIdx.x;
    h[tid] = 0; __syncthreads();
    int b = blockIdx.x;
    int lo = srcBinBase[b], hi = srcBinBase[b + 1];
    for (int i = lo + tid; i < hi; i += BS)
        atomicAdd(&h[srcPart[i]], 1);
    __syncthreads();
    int n = b * 256 + tid;
    if (n < N) out_norm[n] = rsqrtf(fmaxf((float)h[tid], 1.0f));
}

// ---- featw1: featp = fp16(out_norm * (feat @ W1)); one wave/row ----
__global__ void featw1_kernel(const float* __restrict__ feat,
                              const float* __restrict__ W1,
                              const float* __restrict__ out_norm,
                              __half* __restrict__ featp, int N) {
    __shared__ float w[64 * 64];
    int tid = threadIdx.x;
    for (int i = tid; i < 64 * 16; i += BS)
        ((float4*)w)[i] = ((const float4*)W1)[i];
    __syncthreads();
    int wave = tid >> 6, lane = tid & 63;
    int row = blockIdx.x * 4 + wave;
    if (row >= N) return;
    const float4* fr = (const float4*)(feat + (size_t)row * 64);
    float acc = 0.0f;
    #pragma unroll
    for (int k4 = 0; k4 < 16; k4++) {
        float4 a = fr[k4];                         // wave-uniform broadcast
        acc += a.x * w[(4 * k4 + 0) * 64 + lane];  // lane stride-1: conflict-free
        acc += a.y * w[(4 * k4 + 1) * 64 + lane];
        acc += a.z * w[(4 * k4 + 2) * 64 + lane];
        acc += a.w * w[(4 * k4 + 3) * 64 + lane];
    }
    featp[(size_t)row * 64 + lane] = __float2half(out_norm[row] * acc);
}

// ---- agg1: one block per dst bin; LDS f32 accumulate + fused MLP epilogue ----
__global__ __launch_bounds__(256) void agg1_kernel(const int* __restrict__ dstBinBase,
                                                   const int* __restrict__ packed,
                                                   const __half* __restrict__ featp,
                                                   const float* __restrict__ b1,
                                                   const float* __restrict__ W2,
                                                   const float* __restrict__ out_norm,
                                                   float* __restrict__ s_buf,
                                                   float* __restrict__ in_norm_sav, int N) {
    __shared__ float acc[256 * STR];   // [dstLow][feat], pad-65 -> bank=(d+8l+c)%32
    __shared__ int cnt[256];
    __shared__ float b1s[64];
    __shared__ float w2s[64];
    int tid = threadIdx.x;
    for (int i = tid; i < 256 * STR; i += BS) acc[i] = 0.0f;
    cnt[tid] = 0;
    if (tid < 64) { b1s[tid] = b1[tid]; w2s[tid] = W2[tid]; }
    __syncthreads();
    int b = blockIdx.x;
    int lo = dstBinBase[b], hi = dstBinBase[b + 1];
    int w = tid >> 6, lane = tid & 63, g = lane >> 3, l = lane & 7;
    const uint4* fp4 = (const uint4*)featp;
    for (int base = lo + w * 16; base < hi; base += 64) {   // 4 waves x 16 edges
        int e0 = base + g, e1 = base + 8 + g;
        bool p0 = e0 < hi, p1 = e1 < hi;
        int pv0 = p0 ? packed[e0] : 0;
        int pv1 = p1 ? packed[e1] : 0;
        int sn0 = pv0 & 0x1FFFF, d0 = (pv0 >> 17) & 255;
        int sn1 = pv1 & 0x1FFFF, d1 = (pv1 >> 17) & 255;
        uint4 q0 = {0, 0, 0, 0}, q1 = {0, 0, 0, 0};
        if (p0) q0 = fp4[(size_t)sn0 * 8 + l];   // two independent 16B gathers
        if (p1) q1 = fp4[(size_t)sn1 * 8 + l];
        if (l == 0) {
            if (p0) atomicAdd(&cnt[d0], 1);
            if (p1) atomicAdd(&cnt[d1], 1);
        }
        const __half2* h0 = (const __half2*)&q0;
        const __half2* h1 = (const __half2*)&q1;
        if (p0) {
            float* r = &acc[d0 * STR + l * 8];
            #pragma unroll
            for (int c = 0; c < 4; c++) {
                float2 f = __half22float2(h0[c]);
                atomicAdd(&r[2 * c], f.x);
                atomicAdd(&r[2 * c + 1], f.y);
            }
        }
        if (p1) {
            float* r = &acc[d1 * STR + l * 8];
            #pragma unroll
            for (int c = 0; c < 4; c++) {
                float2 f = __half22float2(h1[c]);
                atomicAdd(&r[2 * c], f.x);
                atomicAdd(&r[2 * c + 1], f.y);
            }
        }
    }
    __syncthreads();
    int n = b * 256 + tid;
    if (n < N) {
        float inn = rsqrtf(fmaxf((float)cnt[tid], 1.0f));
        float v = 0.0f;
        #pragma unroll 8
        for (int c = 0; c < 64; c++) {
            float h = fmaxf(inn * acc[tid * STR + c] + b1s[c], 0.0f);
            v += h * w2s[c];
        }
        s_buf[n] = out_norm[n] * v;
        in_norm_sav[n] = inn;
    }
}

// ---- agg2: one block per dst bin; scalar LDS accumulate + sigmoid ----
__global__ void agg2_kernel(const int* __restrict__ dstBinBase, const int* __restrict__ packed,
                            const float* __restrict__ s_buf, const float* __restrict__ in_norm_sav,
                            const float* __restrict__ b2, float* __restrict__ out, int N) {
    __shared__ float acc2[256];
    int tid = threadIdx.x;
    acc2[tid] = 0.0f;
    __syncthreads();
    int b = blockIdx.x;
    int lo = dstBinBase[b], hi = dstBinBase[b + 1];
    for (int i = lo + tid; i < hi; i += BS) {
        int pv = packed[i];
        atomicAdd(&acc2[(pv >> 17) & 255], s_buf[pv & 0x1FFFF]);
    }
    __syncthreads();
    int n = b * 256 + tid;
    if (n < N) {
        float x = in_norm_sav[n] * acc2[tid] + b2[0];
        out[n] = 1.0f / (1.0f + expf(-x));
    }
}

extern "C" void kernel_launch(void* const* d_in, const int* in_sizes, int n_in,
                              void* d_out, int out_size, void* d_ws, size_t ws_size,
                              hipStream_t stream) {
    const float* feat = (const float*)d_in[0];
    const float* W1   = (const float*)d_in[1];
    const float* b1   = (const float*)d_in[2];
    const float* W2   = (const float*)d_in[3];
    const float* b2   = (const float*)d_in[4];
    const int* src = (const int*)d_in[5];
    const int* dst = (const int*)d_in[6];
    float* out = (float*)d_out;

    const int N  = in_sizes[0] / 64;        // 50000
    const int E  = in_sizes[5];             // 800000
    const int NB = (N + 255) >> 8;          // 196 bins of 256 nodes
    const int TD = (E + EPB - 1) / EPB;     // 782 hist/partition blocks

    // workspace: counts matrices | binBases | packed | srcPart bytes | featp | floats
    int* wsi = (int*)d_ws;
    int* countsD    = wsi;                               // NB*TD
    int* countsS    = countsD + (size_t)NB * TD;         // NB*TD
    int* dstBinBase = countsS + (size_t)NB * TD;         // NB+1
    int* srcBinBase = dstBinBase + NB + 1;               // NB+1
    int* packed     = srcBinBase + NB + 1;               // E
    unsigned char* srcPart = (unsigned char*)(packed + E);  // E bytes
    size_t off_b = (2 * (size_t)NB * TD + 2 * (NB + 1) + (size_t)E) * sizeof(int) + (size_t)E;
    off_b = (off_b + 15) & ~(size_t)15;
    __half* featp      = (__half*)((char*)d_ws + off_b);                           // 64N
    float*  out_norm   = (float*)((char*)d_ws + off_b + (size_t)64 * N * sizeof(__half)); // N
    float*  s_buf      = out_norm + N;                   // N
    float*  in_norm_sav = s_buf + N;                     // N

    hist_kernel<<<TD, BS, 0, stream>>>(src, dst, countsD, countsS, E, NB, TD);
    scan_kernel<<<2, 256, 0, stream>>>(countsD, countsS, dstBinBase, srcBinBase, NB, TD);
    partition_kernel<<<TD, BS, 0, stream>>>(src, dst, countsD, countsS, packed, srcPart, E, NB, TD);
    srcfin_kernel<<<NB, BS, 0, stream>>>(srcBinBase, srcPart, out_norm, N, NB);
    featw1_kernel<<<(N + 3) / 4, BS, 0, stream>>>(feat, W1, out_norm, featp, N);
    agg1_kernel<<<NB, BS, 0, stream>>>(dstBinBase, packed, featp, b1, W2, out_norm, s_buf, in_norm_sav, N);
    agg2_kernel<<<NB, BS, 0, stream>>>(dstBinBase, packed, s_buf, in_norm_sav, b2, out, N);
}

// Round 12
// 401.406 us; speedup vs baseline: 1.3894x; 1.3894x over previous
//
#include <hip/hip_runtime.h>
#include <hip/hip_fp16.h>
#include <math.h>

// GCN 2-layer (DGL GraphConv norm='both') as ONE persistent kernel.
// Round-12 rationale: fitting rounds 2-11 gives dur ~= 16-20us per dispatch +
// kernel work; with 7-9 dispatches we paid ~140us of pure launch overhead on
// ~60us of work. This version: 1 memset (barrier counters) + 1 kernel.
// 512 blocks x 256 thr (2 blocks/CU co-resident: 24.6KB LDS, lb(256,2));
// software grid barrier = 8 spread device-scope counters, monotonic targets.
// Phases (proven round-9/10 bodies, grid-strided):
//  P1 edge bin-hist (LDS int atomics) + raw featp=fp16(feat@W1)
//  P2 exclusive scan of each [bin][block] counts row
//  P3 partition edges into 256-node dst bins (deterministic bases, no global
//     atomics; inline top-scan; writes binBases) + src-low bytes into src bins
//  P4 per-src-bin hist -> out_norm; scale featp rows by out_norm
//  P5 per-dst-bin counting sort -> csr_src / row_start / in_deg
//  P6 agg1: wave/node, 8 edge-groups x 8 fp16 chunks, unroll-2, register acc
//  P7 agg2: 16 lanes/node + sigmoid -> out
// Requires N <= 65536 (NB<=256, src in 17 bits). N=50000, E=800000.

#define BS   256
#define NBLK 512
#define NBAR 8

__device__ __forceinline__ void gbar(int* bar, int phase) {
    __syncthreads();
    if (threadIdx.x == 0) {
        __threadfence();   // release: make this block's stores device-visible
        __hip_atomic_fetch_add(&bar[(blockIdx.x & (NBAR - 1)) * 32], 1,
                               __ATOMIC_RELAXED, __HIP_MEMORY_SCOPE_AGENT);
        const int target = NBLK * phase;
        int sum;
        do {
            sum = 0;
            #pragma unroll
            for (int i = 0; i < NBAR; i++)
                sum += __hip_atomic_load(&bar[i * 32], __ATOMIC_RELAXED,
                                         __HIP_MEMORY_SCOPE_AGENT);
        } while (sum < target);
        __threadfence();   // acquire: invalidate stale cached lines
    }
    __syncthreads();
}

__global__ __launch_bounds__(BS, 2) void gcn_persist(
    const float* __restrict__ feat, const float* __restrict__ W1,
    const float* __restrict__ b1, const float* __restrict__ W2,
    const float* __restrict__ b2, const int* __restrict__ src,
    const int* __restrict__ dst,
    int* bar, int* countsD, int* countsS, int* rowSumD, int* rowSumS,
    int* dstBinBase, int* srcBinBase, int* packed, unsigned char* srcPart,
    int* csr_src, int* in_deg, int* row_start, float* out_norm, float* s_buf,
    __half* featp, float* out, int N, int E, int NB)
{
    __shared__ float w[64 * 64];   // 16 KB
    __shared__ int hA[256];
    __shared__ int hB[256];
    __shared__ int sc[256];
    __shared__ int rbD[256];
    __shared__ int rbS[256];
    __shared__ int curD[256];
    __shared__ int curS[256];
    __shared__ float onorm[256];

    const int tid  = threadIdx.x;
    const int b    = blockIdx.x;
    const int wv   = tid >> 6;
    const int lane = tid & 63;
    const int EB   = (E + NBLK - 1) / NBLK;
    const int elo  = b * EB;
    const int ehi  = (elo + EB < E) ? elo + EB : E;

    // ---------------- P1: edge hist + raw featp = fp16(feat @ W1) ------------
    hA[tid] = 0; hB[tid] = 0;
    for (int i = tid; i < 64 * 16; i += BS)
        ((float4*)w)[i] = ((const float4*)W1)[i];
    __syncthreads();
    for (int e = elo + tid; e < ehi; e += BS) {
        atomicAdd(&hA[dst[e] >> 8], 1);     // LDS int atomics: native, fast
        atomicAdd(&hB[src[e] >> 8], 1);
    }
    __syncthreads();
    if (tid < NB) {
        countsD[(size_t)tid * NBLK + b] = hA[tid];
        countsS[(size_t)tid * NBLK + b] = hB[tid];
    }
    for (int row = b * 4 + wv; row < N; row += NBLK * 4) {
        const float4* fr = (const float4*)(feat + (size_t)row * 64);
        float acc = 0.0f;
        #pragma unroll
        for (int k4 = 0; k4 < 16; k4++) {
            float4 a = fr[k4];                          // wave-uniform broadcast
            acc += a.x * w[(4 * k4 + 0) * 64 + lane];   // stride-1: conflict-free
            acc += a.y * w[(4 * k4 + 1) * 64 + lane];
            acc += a.z * w[(4 * k4 + 2) * 64 + lane];
            acc += a.w * w[(4 * k4 + 3) * 64 + lane];
        }
        featp[(size_t)row * 64 + lane] = __float2half(acc);   // unnormalized
    }
    gbar(bar, 1);

    // ---------------- P2: exclusive-scan each counts row (len NBLK) ----------
    if (b < 2 * NB) {
        int* row = (b < NB) ? (countsD + (size_t)b * NBLK)
                            : (countsS + (size_t)(b - NB) * NBLK);
        int a0 = row[2 * tid], a1 = row[2 * tid + 1];
        int s01 = a0 + a1;
        sc[tid] = s01; __syncthreads();
        for (int off = 1; off < 256; off <<= 1) {
            int u = (tid >= off) ? sc[tid - off] : 0; __syncthreads();
            sc[tid] += u; __syncthreads();
        }
        int ex = sc[tid] - s01;
        row[2 * tid] = ex; row[2 * tid + 1] = ex + a0;
        if (tid == 255) {
            if (b < NB) rowSumD[b] = sc[255];
            else        rowSumS[b - NB] = sc[255];
        }
    }
    gbar(bar, 2);

    // ---------------- P3: partition (inline top-scan; no global atomics) -----
    {
        int vD = (tid < NB) ? rowSumD[tid] : 0;
        sc[tid] = vD; __syncthreads();
        for (int off = 1; off < 256; off <<= 1) {
            int u = (tid >= off) ? sc[tid - off] : 0; __syncthreads();
            sc[tid] += u; __syncthreads();
        }
        rbD[tid] = sc[tid] - vD;
        __syncthreads();
        int vS = (tid < NB) ? rowSumS[tid] : 0;
        sc[tid] = vS; __syncthreads();
        for (int off = 1; off < 256; off <<= 1) {
            int u = (tid >= off) ? sc[tid - off] : 0; __syncthreads();
            sc[tid] += u; __syncthreads();
        }
        rbS[tid] = sc[tid] - vS;
        __syncthreads();
        if (b == 0) {
            if (tid < NB) { dstBinBase[tid] = rbD[tid]; srcBinBase[tid] = rbS[tid]; }
            if (tid == NB) {
                dstBinBase[NB] = rbD[NB - 1] + rowSumD[NB - 1];
                srcBinBase[NB] = rbS[NB - 1] + rowSumS[NB - 1];
            }
        }
        if (tid < NB) {
            curD[tid] = rbD[tid] + countsD[(size_t)tid * NBLK + b];
            curS[tid] = rbS[tid] + countsS[(size_t)tid * NBLK + b];
        }
        __syncthreads();
        for (int e = elo + tid; e < ehi; e += BS) {
            int d = dst[e], s2 = src[e];
            int pos = atomicAdd(&curD[d >> 8], 1);            // LDS atomic only
            packed[pos] = s2 | ((d & 255) << 17);
            int pos2 = atomicAdd(&curS[s2 >> 8], 1);
            srcPart[pos2] = (unsigned char)(s2 & 255);
        }
    }
    gbar(bar, 3);

    // ---------------- P4: src-bin hist -> out_norm; scale featp rows ---------
    if (b < NB) {
        int lo = srcBinBase[b], hi = srcBinBase[b + 1];
        hA[tid] = 0; __syncthreads();
        for (int i = lo + tid; i < hi; i += BS)
            atomicAdd(&hA[srcPart[i]], 1);
        __syncthreads();
        float on = rsqrtf(fmaxf((float)hA[tid], 1.0f));
        onorm[tid] = on;
        int n = b * 256 + tid;
        if (n < N) out_norm[n] = on;
        __syncthreads();
        __half2* base2 = (__half2*)(featp + (size_t)b * 256 * 64);
        int rows = N - b * 256; if (rows > 256) rows = 256;
        int cap = rows * 32;                      // 32 half2 per row
        for (int idx = tid; idx < cap; idx += BS) {
            float s2 = onorm[idx >> 5];
            float2 f = __half22float2(base2[idx]);
            base2[idx] = __floats2half2_rn(f.x * s2, f.y * s2);
        }
    }
    gbar(bar, 4);

    // ---------------- P5: per-dst-bin counting sort -> CSR -------------------
    if (b < NB) {
        int lo = dstBinBase[b], hi = dstBinBase[b + 1];
        hA[tid] = 0; __syncthreads();
        for (int i = lo + tid; i < hi; i += BS)
            atomicAdd(&hA[(packed[i] >> 17) & 255], 1);
        __syncthreads();
        int v = hA[tid];
        sc[tid] = v; __syncthreads();
        for (int off = 1; off < 256; off <<= 1) {
            int u = (tid >= off) ? sc[tid - off] : 0; __syncthreads();
            sc[tid] += u; __syncthreads();
        }
        int ex = sc[tid] - v;
        int n = b * 256 + tid;
        if (n < N) { in_deg[n] = v; row_start[n] = lo + ex; }
        curD[tid] = lo + ex;
        __syncthreads();
        for (int i = lo + tid; i < hi; i += BS) {
            int pv = packed[i];
            int pos = atomicAdd(&curD[(pv >> 17) & 255], 1);
            csr_src[pos] = pv & 0x1FFFF;
        }
    }
    gbar(bar, 5);

    // ---------------- P6: agg1 — wave/node, register acc, unroll-2 -----------
    {
        int g = lane >> 3, l = lane & 7;
        const uint4* fp4 = (const uint4*)featp;
        for (int n = b * 4 + wv; n < N; n += NBLK * 4) {
            int start = row_start[n];
            int deg = in_deg[n];
            float acc[8] = {0, 0, 0, 0, 0, 0, 0, 0};
            for (int j = 0; j < deg; j += 16) {
                int e0 = j + g, e1 = j + 8 + g;
                bool p0 = e0 < deg, p1 = e1 < deg;
                int sn0 = p0 ? csr_src[start + e0] : 0;
                int sn1 = p1 ? csr_src[start + e1] : 0;
                uint4 q0 = {0, 0, 0, 0}, q1 = {0, 0, 0, 0};
                if (p0) q0 = fp4[(size_t)sn0 * 8 + l];   // 2 independent gathers
                if (p1) q1 = fp4[(size_t)sn1 * 8 + l];
                const __half2* h0 = (const __half2*)&q0;
                const __half2* h1 = (const __half2*)&q1;
                #pragma unroll
                for (int c = 0; c < 4; c++) {
                    float2 f0 = __half22float2(h0[c]);
                    float2 f1 = __half22float2(h1[c]);
                    acc[2 * c]     += f0.x + f1.x;
                    acc[2 * c + 1] += f0.y + f1.y;
                }
            }
            #pragma unroll
            for (int off = 8; off < 64; off <<= 1) {
                #pragma unroll
                for (int c = 0; c < 8; c++)
                    acc[c] += __shfl_xor(acc[c], off, 64);
            }
            float inn = rsqrtf(fmaxf((float)deg, 1.0f));
            float v2 = 0.0f;
            #pragma unroll
            for (int c = 0; c < 8; c++) {
                float h = fmaxf(inn * acc[c] + b1[l * 8 + c], 0.0f);
                v2 += h * W2[l * 8 + c];
            }
            #pragma unroll
            for (int off = 1; off < 8; off <<= 1)
                v2 += __shfl_xor(v2, off, 64);
            if (lane == 0) s_buf[n] = out_norm[n] * v2;
        }
    }
    gbar(bar, 6);

    // ---------------- P7: agg2 — 16 lanes/node + sigmoid ---------------------
    {
        int sid = (b * BS + tid) >> 4;
        int sub = lane & 15;
        for (int n = sid; n < N; n += NBLK * (BS / 16)) {
            int start = row_start[n], deg = in_deg[n];
            float a = 0.0f;
            for (int j = sub; j < deg; j += 32) {
                int j1 = j + 16;
                int i0 = csr_src[start + j];
                int i1 = (j1 < deg) ? csr_src[start + j1] : 0;
                float v0 = s_buf[i0];
                float v1 = (j1 < deg) ? s_buf[i1] : 0.0f;
                a += v0 + v1;
            }
            #pragma unroll
            for (int off = 1; off < 16; off <<= 1)
                a += __shfl_xor(a, off, 64);
            if (sub == 0) {
                float x = rsqrtf(fmaxf((float)deg, 1.0f)) * a + b2[0];
                out[n] = 1.0f / (1.0f + expf(-x));
            }
        }
    }
}

extern "C" void kernel_launch(void* const* d_in, const int* in_sizes, int n_in,
                              void* d_out, int out_size, void* d_ws, size_t ws_size,
                              hipStream_t stream) {
    const float* feat = (const float*)d_in[0];
    const float* W1   = (const float*)d_in[1];
    const float* b1   = (const float*)d_in[2];
    const float* W2   = (const float*)d_in[3];
    const float* b2   = (const float*)d_in[4];
    const int* src = (const int*)d_in[5];
    const int* dst = (const int*)d_in[6];
    float* out = (float*)d_out;

    const int N  = in_sizes[0] / 64;   // 50000
    const int E  = in_sizes[5];        // 800000
    const int NB = (N + 255) >> 8;     // 196 (must be <= 256)

    int* wsi = (int*)d_ws;
    int* bar        = wsi;                                  // NBAR*32 ints
    int* countsD    = bar + NBAR * 32;                      // NB*NBLK
    int* countsS    = countsD + (size_t)NB * NBLK;          // NB*NBLK
    int* rowSumD    = countsS + (size_t)NB * NBLK;          // NB
    int* rowSumS    = rowSumD + NB;                         // NB
    int* dstBinBase = rowSumS + NB;                         // NB+1
    int* srcBinBase = dstBinBase + NB + 1;                  // NB+1
    int* packed     = srcBinBase + NB + 1;                  // E
    int* csr_src    = packed + E;                           // E
    int* in_deg     = csr_src + E;                          // N
    int* row_start  = in_deg + N;                           // N
    unsigned char* srcPart = (unsigned char*)(row_start + N);  // E bytes
    size_t off_b = ((size_t)NBAR * 32 + 2 * (size_t)NB * NBLK + 2 * NB +
                    2 * (NB + 1) + 2 * (size_t)E + 2 * (size_t)N) * sizeof(int)
                   + (size_t)E;
    off_b = (off_b + 15) & ~(size_t)15;
    __half* featp    = (__half*)((char*)d_ws + off_b);                     // 64N
    float*  out_norm = (float*)((char*)d_ws + off_b + (size_t)64 * N * sizeof(__half));
    float*  s_buf    = out_norm + N;                        // N

    // zero only the barrier counters (monotonic targets; re-zeroed every call)
    hipMemsetAsync(bar, 0, (size_t)NBAR * 32 * sizeof(int), stream);

    gcn_persist<<<NBLK, BS, 0, stream>>>(
        feat, W1, b1, W2, b2, src, dst,
        bar, countsD, countsS, rowSumD, rowSumS, dstBinBase, srcBinBase,
        packed, srcPart, csr_src, in_deg, row_start, out_norm, s_buf,
        featp, out, N, E, NB);
}